// Round 5
// baseline (187.336 us; speedup 1.0000x reference)
//
#include <hip/hip_runtime.h>
#include <hip/hip_bf16.h>
#include <math.h>

#define NROWS   16384
#define IN_DIM  64
#define HID     256
#define OUT_DIM 64
#define NEXP    256
#define MT      32     // rows per tile (2 blocks/expert, both active)
#define HP      264    // padded LDS row stride (bf16 elems): 528 B, 16B-aligned

typedef __attribute__((ext_vector_type(8))) short short8;   // 8 bf16 (4 VGPRs)
typedef __attribute__((ext_vector_type(4))) float f32x4;
typedef __attribute__((ext_vector_type(4))) unsigned uint4v;
typedef __attribute__((ext_vector_type(2))) unsigned uint2v;

// ---------------- fused bucketing kernel (single block) ----------------

__global__ __launch_bounds__(1024) void prep_k(const int* __restrict__ ind,
                                               int* __restrict__ rows,
                                               int* __restrict__ offsets) {
  __shared__ int hist[NEXP];
  __shared__ int scan[NEXP];
  __shared__ int cur[NEXP];
  int t = threadIdx.x;
  if (t < NEXP) hist[t] = 0;
  __syncthreads();
  for (int n = t; n < NROWS; n += 1024) atomicAdd(&hist[ind[n]], 1);
  __syncthreads();
  if (t < NEXP) scan[t] = hist[t];
  __syncthreads();
  for (int d = 1; d < NEXP; d <<= 1) {
    int v = (t < NEXP && t >= d) ? scan[t - d] : 0;
    __syncthreads();
    if (t < NEXP) scan[t] += v;
    __syncthreads();
  }
  if (t < NEXP) {
    int exc = scan[t] - hist[t];
    offsets[t] = exc;
    cur[t] = exc;
    if (t == NEXP - 1) offsets[NEXP] = scan[t];
  }
  __syncthreads();
  for (int n = t; n < NROWS; n += 1024) {
    int p = atomicAdd(&cur[ind[n]], 1);
    rows[p] = n;
  }
}

// ---------------- helpers ----------------

// Truncating fp32->bf16 pack: 2 VALU insts per pair. Weights only (<=1 ulp).
__device__ __forceinline__ unsigned pk2_trunc(float a, float b) {
  unsigned ua = __builtin_bit_cast(unsigned, a);
  unsigned ub = __builtin_bit_cast(unsigned, b);
  return (ub & 0xffff0000u) | (ua >> 16);
}

// RNE pack via HW packed convert (activations / x staging).
__device__ __forceinline__ unsigned pk2_rn(float a, float b) {
  __hip_bfloat162 h = __float22bfloat162_rn(float2{a, b});
  unsigned r;
  __builtin_memcpy(&r, &h, 4);
  return r;
}

__device__ __forceinline__ short8 cvt8w(f32x4 w0, f32x4 w1) {
  uint4v u;
  u.x = pk2_trunc(w0.x, w0.y);
  u.y = pk2_trunc(w0.z, w0.w);
  u.z = pk2_trunc(w1.x, w1.y);
  u.w = pk2_trunc(w1.z, w1.w);
  return __builtin_bit_cast(short8, u);
}

__device__ __forceinline__ float fast_tanh(float v) {
  float e = __expf(2.f * v);
  return 1.f - 2.f * __builtin_amdgcn_rcpf(e + 1.f);
}

// One layer as MFMA 16x16x32 bf16, neurons on M, data rows on N.
// Distance-1 register double-buffer on the global weight stream.
template <int K, int NMT, int NNT>
__device__ __forceinline__ void layer_mm(const float* __restrict__ Wp,
                                         const float* __restrict__ bp,
                                         const unsigned short* Hin,
                                         int l15, int q, f32x4 (&acc)[NMT][NNT]) {
#pragma unroll
  for (int mt = 0; mt < NMT; mt++) {
    f32x4 bv = *(const f32x4*)(bp + mt * 16 + q * 4);
#pragma unroll
    for (int nt = 0; nt < NNT; nt++) acc[mt][nt] = bv;
  }
  const float* wr[NMT];
#pragma unroll
  for (int mt = 0; mt < NMT; mt++)
    wr[mt] = Wp + (size_t)(mt * 16 + l15) * K + q * 8;

  constexpr int KS = K / 32;
  f32x4 wcur[NMT][2], wnxt[NMT][2];
#pragma unroll
  for (int mt = 0; mt < NMT; mt++) {
    wcur[mt][0] = *(const f32x4*)(wr[mt]);
    wcur[mt][1] = *(const f32x4*)(wr[mt] + 4);
  }
#pragma unroll
  for (int ks = 0; ks < KS; ks++) {
    int kn = (ks + 1 < KS) ? (ks + 1) * 32 : 0;  // dummy wrap on last iter
#pragma unroll
    for (int mt = 0; mt < NMT; mt++) {
      wnxt[mt][0] = *(const f32x4*)(wr[mt] + kn);
      wnxt[mt][1] = *(const f32x4*)(wr[mt] + kn + 4);
    }
    short8 bfr[NNT];
#pragma unroll
    for (int nt = 0; nt < NNT; nt++)
      bfr[nt] = *(const short8*)&Hin[(nt * 16 + l15) * HP + ks * 32 + q * 8];
#pragma unroll
    for (int mt = 0; mt < NMT; mt++) {
      short8 a = cvt8w(wcur[mt][0], wcur[mt][1]);
#pragma unroll
      for (int nt = 0; nt < NNT; nt++)
        acc[mt][nt] =
            __builtin_amdgcn_mfma_f32_16x16x32_bf16(a, bfr[nt], acc[mt][nt], 0, 0, 0);
    }
#pragma unroll
    for (int mt = 0; mt < NMT; mt++) {
      wcur[mt][0] = wnxt[mt][0];
      wcur[mt][1] = wnxt[mt][1];
    }
  }
}

// tanh + RNE pack + store h-frags.
template <int NNT>
__device__ __forceinline__ void write_h(f32x4 (&acc)[4][NNT], unsigned short* H,
                                        int w, int l15, int q) {
#pragma unroll
  for (int mt = 0; mt < 4; mt++)
#pragma unroll
    for (int nt = 0; nt < NNT; nt++) {
      uint2v v;
      v.x = pk2_rn(fast_tanh(acc[mt][nt].x), fast_tanh(acc[mt][nt].y));
      v.y = pk2_rn(fast_tanh(acc[mt][nt].z), fast_tanh(acc[mt][nt].w));
      *(uint2v*)&H[(nt * 16 + l15) * HP + w * 64 + mt * 16 + q * 4] = v;
    }
}

// ---------------- main MLP kernel ----------------

__global__ __launch_bounds__(256, 2) void mlp_k(
    const float* __restrict__ x,
    const float* __restrict__ W1, const float* __restrict__ b1,
    const float* __restrict__ W2, const float* __restrict__ b2,
    const float* __restrict__ Wl, const float* __restrict__ bl,
    const int* __restrict__ rows, const int* __restrict__ offsets,
    float* __restrict__ out) {
  __shared__ __align__(16) unsigned short H[MT * HP];  // 16896 B

  const int t = threadIdx.x;
  const int w = t >> 6;          // wave 0..3
  const int l15 = t & 15;
  const int q = (t >> 4) & 3;    // quad within wave
  const int e = blockIdx.x & 255;   // expert; pair (b, b+256) -> same XCD
  const int j = blockIdx.x >> 8;    // half 0/1
  const int beg = offsets[e];
  const int cnt = offsets[e + 1] - beg;

  const float* W1e = W1 + (size_t)e * HID * IN_DIM + (size_t)(w * 64) * IN_DIM;
  const float* W2e = W2 + (size_t)e * HID * HID + (size_t)(w * 64) * HID;
  const float* Wle = Wl + (size_t)e * OUT_DIM * HID + (size_t)(w * 16) * HID;
  const float* b1e = b1 + e * HID + w * 64;
  const float* b2e = b2 + e * HID + w * 64;
  const float* ble = bl + e * OUT_DIM + w * 16;

  const int sm = t >> 3;             // x-staging: row (0..31)
  const int sc = (t & 7) * 8;        // x-staging: col base (8 floats/thread)

  for (int mt0 = j * MT; mt0 < cnt; mt0 += 2 * MT) {
    __syncthreads();  // prev tile's l3 reads done before x-stage overwrites H
    // ---- stage x tile (fp32 global -> bf16 LDS cols 0..63), zero-pad tail rows
    {
      int gm = mt0 + sm;
      bool val = gm < cnt;
      int r = val ? rows[beg + gm] : 0;
      const float* xr = x + (size_t)r * IN_DIM + sc;
      uint4v u;
      if (val) {
        f32x4 a0 = *(const f32x4*)(xr);
        f32x4 a1 = *(const f32x4*)(xr + 4);
        u.x = pk2_rn(a0.x, a0.y); u.y = pk2_rn(a0.z, a0.w);
        u.z = pk2_rn(a1.x, a1.y); u.w = pk2_rn(a1.z, a1.w);
      } else {
        u = (uint4v){0, 0, 0, 0};
      }
      *(uint4v*)&H[sm * HP + sc] = u;
    }
    __syncthreads();

    // ---- layer1: x(K=64) -> h1(256 neurons), tanh
    {
      f32x4 acc[4][2];
      layer_mm<IN_DIM, 4, 2>(W1e, b1e, H, l15, q, acc);
      __syncthreads();  // all x reads done before h1 writes clobber H
      write_h<2>(acc, H, w, l15, q);
    }
    __syncthreads();

    // ---- layer2: h1(K=256) -> h2(256), tanh (in-place region)
    {
      f32x4 acc[4][2];
      layer_mm<HID, 4, 2>(W2e, b2e, H, l15, q, acc);
      __syncthreads();  // all h1 reads done before h2 writes
      write_h<2>(acc, H, w, l15, q);
    }
    __syncthreads();

    // ---- layer3: h2(K=256) -> out (64 neurons); wave w owns neurons w*16..+15
    {
      f32x4 acc[1][2];
      layer_mm<HID, 1, 2>(Wle, ble, H, l15, q, acc);
#pragma unroll
      for (int nt = 0; nt < 2; nt++) {
        int gm = mt0 + nt * 16 + l15;
        if (gm < cnt) {
          int r = rows[beg + gm];
          *(f32x4*)(out + (size_t)r * OUT_DIM + w * 16 + q * 4) = acc[0][nt];
        }
      }
    }
  }
}

// ---------------- launcher ----------------

extern "C" void kernel_launch(void* const* d_in, const int* in_sizes, int n_in,
                              void* d_out, int out_size, void* d_ws, size_t ws_size,
                              hipStream_t stream) {
  const float* x   = (const float*)d_in[0];
  const int*   ind = (const int*)d_in[1];
  const float* W1  = (const float*)d_in[2];
  const float* b1  = (const float*)d_in[3];
  const float* W2  = (const float*)d_in[4];
  const float* b2  = (const float*)d_in[5];
  const float* Wl  = (const float*)d_in[6];
  const float* bl  = (const float*)d_in[7];
  float* out = (float*)d_out;

  int* offsets = (int*)d_ws;        // 257 ints
  int* rows    = (int*)d_ws + 260;  // 16384 ints

  prep_k<<<1, 1024, 0, stream>>>(ind, rows, offsets);
  mlp_k<<<NEXP * 2, 256, 0, stream>>>(x, W1, b1, W2, b2, Wl, bl, rows, offsets, out);
}

// Round 6
// 171.053 us; speedup vs baseline: 1.0952x; 1.0952x over previous
//
#include <hip/hip_runtime.h>
#include <hip/hip_bf16.h>
#include <math.h>

#define NROWS   16384
#define IN_DIM  64
#define HID     256
#define OUT_DIM 64
#define NEXP    256
#define MT      112    // row slots per block (cnt ~ 64+-8; loop covers >112 tail)
#define HP      264    // padded LDS row stride in bf16 elems (528 B): bank-spread, 16B-aligned

typedef __attribute__((ext_vector_type(8))) short short8;   // 8 bf16 (4 VGPRs)
typedef __attribute__((ext_vector_type(4))) float f32x4;
typedef __attribute__((ext_vector_type(4))) unsigned uint4v;
typedef __attribute__((ext_vector_type(2))) unsigned uint2v;

// ---------------- fused bucketing kernel (single block) ----------------

__global__ __launch_bounds__(1024) void prep_k(const int* __restrict__ ind,
                                               int* __restrict__ rows,
                                               int* __restrict__ offsets) {
  __shared__ int hist[NEXP];
  __shared__ int scan[NEXP];
  __shared__ int cur[NEXP];
  int t = threadIdx.x;
  if (t < NEXP) hist[t] = 0;
  __syncthreads();
  for (int n = t; n < NROWS; n += 1024) atomicAdd(&hist[ind[n]], 1);
  __syncthreads();
  if (t < NEXP) scan[t] = hist[t];
  __syncthreads();
  for (int d = 1; d < NEXP; d <<= 1) {
    int v = (t < NEXP && t >= d) ? scan[t - d] : 0;
    __syncthreads();
    if (t < NEXP) scan[t] += v;
    __syncthreads();
  }
  if (t < NEXP) {
    int exc = scan[t] - hist[t];
    offsets[t] = exc;
    cur[t] = exc;
    if (t == NEXP - 1) offsets[NEXP] = scan[t];
  }
  __syncthreads();
  for (int n = t; n < NROWS; n += 1024) {
    int p = atomicAdd(&cur[ind[n]], 1);
    rows[p] = n;
  }
}

// ---------------- helpers ----------------

// Truncating fp32->bf16 pack: 2 VALU insts/pair. Weights only (<=1 ulp).
__device__ __forceinline__ unsigned pk2_trunc(float a, float b) {
  unsigned ua = __builtin_bit_cast(unsigned, a);
  unsigned ub = __builtin_bit_cast(unsigned, b);
  return (ub & 0xffff0000u) | (ua >> 16);
}

// RNE pack (activations).
__device__ __forceinline__ unsigned pk2_rn(float a, float b) {
  __hip_bfloat162 h = __float22bfloat162_rn(float2{a, b});
  unsigned r;
  __builtin_memcpy(&r, &h, 4);
  return r;
}

__device__ __forceinline__ short8 cvt8w(f32x4 w0, f32x4 w1) {
  uint4v u;
  u.x = pk2_trunc(w0.x, w0.y);
  u.y = pk2_trunc(w0.z, w0.w);
  u.z = pk2_trunc(w1.x, w1.y);
  u.w = pk2_trunc(w1.z, w1.w);
  return __builtin_bit_cast(short8, u);
}

__device__ __forceinline__ float fast_tanh(float v) {
  float e = __expf(2.f * v);
  return 1.f - 2.f * __builtin_amdgcn_rcpf(e + 1.f);
}

// One layer slab, NMT=1: this wave owns 16 output neurons (weight rows at wr,
// already lane-resolved: + (base_row + l15)*K + q*8). Distance-2 register
// prefetch on the global weight stream (3-stage rotating buffer).
// Hin: LDS activations [MT][HP] bf16. acc[nt]: D frags for row-tiles.
template <int K, int NNT>
__device__ __forceinline__ void layer_mm1(const float* __restrict__ wr,
                                          f32x4 bv,
                                          const unsigned short* __restrict__ Hin,
                                          int l15, int q, f32x4 (&acc)[NNT]) {
  constexpr int KS = K / 32;
#pragma unroll
  for (int nt = 0; nt < NNT; nt++) acc[nt] = bv;
  f32x4 wbuf[3][2];
  wbuf[0][0] = *(const f32x4*)(wr);
  wbuf[0][1] = *(const f32x4*)(wr + 4);
  if (KS > 1) {
    wbuf[1][0] = *(const f32x4*)(wr + 32);
    wbuf[1][1] = *(const f32x4*)(wr + 36);
  }
#pragma unroll
  for (int ks = 0; ks < KS; ks++) {
    if (ks + 2 < KS) {
      wbuf[(ks + 2) % 3][0] = *(const f32x4*)(wr + (ks + 2) * 32);
      wbuf[(ks + 2) % 3][1] = *(const f32x4*)(wr + (ks + 2) * 32 + 4);
    }
    short8 a = cvt8w(wbuf[ks % 3][0], wbuf[ks % 3][1]);
#pragma unroll
    for (int nt = 0; nt < NNT; nt++) {
      short8 b = *(const short8*)&Hin[(nt * 16 + l15) * HP + ks * 32 + q * 8];
      acc[nt] = __builtin_amdgcn_mfma_f32_16x16x32_bf16(a, b, acc[nt], 0, 0, 0);
    }
  }
}

// tanh + RNE pack + store h-frags. col = this wave's neuron-col base (+q*4).
template <int NNT>
__device__ __forceinline__ void write_h1(f32x4 (&acc)[NNT], unsigned short* H,
                                         int col, int l15) {
#pragma unroll
  for (int nt = 0; nt < NNT; nt++) {
    uint2v v;
    v.x = pk2_rn(fast_tanh(acc[nt].x), fast_tanh(acc[nt].y));
    v.y = pk2_rn(fast_tanh(acc[nt].z), fast_tanh(acc[nt].w));
    *(uint2v*)&H[(nt * 16 + l15) * HP + col] = v;
  }
}

// ---------------- main MLP kernel ----------------
// One block per expert; 1024 threads = 16 waves (4/SIMD, 50% occupancy).
// Wave w owns neurons w*16..w*16+15 in layers 1/2; layer 3 (64 neurons):
// wave w owns neuron-tile (w&3), row-tiles (w>>2) and (w>>2)+4.

__global__ __launch_bounds__(1024, 4) void mlp_k(
    const float* __restrict__ x,
    const float* __restrict__ W1, const float* __restrict__ b1,
    const float* __restrict__ W2, const float* __restrict__ b2,
    const float* __restrict__ Wl, const float* __restrict__ bl,
    const int* __restrict__ rows, const int* __restrict__ offsets,
    float* __restrict__ out) {
  __shared__ __align__(16) unsigned short H[MT * HP];  // 59136 B

  const int t = threadIdx.x;
  const int w = t >> 6;          // wave 0..15
  const int l15 = t & 15;
  const int q = (t >> 4) & 3;    // quad within wave
  const int e = blockIdx.x;      // expert
  const int beg = offsets[e];
  const int cnt = offsets[e + 1] - beg;

  const float* W1e = W1 + (size_t)e * HID * IN_DIM + (size_t)(w * 16 + l15) * IN_DIM + q * 8;
  const float* W2e = W2 + (size_t)e * HID * HID + (size_t)(w * 16 + l15) * HID + q * 8;
  const int m3 = w & 3;              // layer-3 neuron tile
  const int ntA = w >> 2;            // layer-3 first row-tile
  const int nt1 = (ntA + 4 < 7) ? ntA + 4 : 6;  // clamped (dup compute, store guarded)
  const float* Wle = Wl + (size_t)e * OUT_DIM * HID + (size_t)(m3 * 16 + l15) * HID + q * 8;
  const f32x4 b1v = *(const f32x4*)(b1 + e * HID + w * 16 + q * 4);
  const f32x4 b2v = *(const f32x4*)(b2 + e * HID + w * 16 + q * 4);
  const f32x4 blv = *(const f32x4*)(bl + e * OUT_DIM + m3 * 16 + q * 4);

  const int sm = t >> 3;             // x-staging: row (0..127, use <112)
  const int sc = (t & 7) * 8;        // x-staging: col base (8 floats)

  for (int mt0 = 0; mt0 < cnt; mt0 += MT) {
    if (mt0) __syncthreads();  // protect H reuse across (rare) extra tiles
    // ---- stage x tile (fp32 global -> bf16 LDS cols 0..63), zero-pad tail
    if (sm < MT) {
      int gm = mt0 + sm;
      bool val = gm < cnt;
      int r = val ? rows[beg + gm] : 0;
      const float* xr = x + (size_t)r * IN_DIM + sc;
      uint4v u;
      if (val) {
        f32x4 a0 = *(const f32x4*)(xr);
        f32x4 a1 = *(const f32x4*)(xr + 4);
        u.x = pk2_rn(a0.x, a0.y); u.y = pk2_rn(a0.z, a0.w);
        u.z = pk2_rn(a1.x, a1.y); u.w = pk2_rn(a1.z, a1.w);
      } else {
        u = (uint4v){0, 0, 0, 0};
      }
      *(uint4v*)&H[sm * HP + sc] = u;
    }
    __syncthreads();

    // ---- layer1: x(K=64) -> h1 (wave's 16 neurons), tanh
    {
      f32x4 acc[7];
      layer_mm1<IN_DIM, 7>(W1e, b1v, H, l15, q, acc);
      __syncthreads();  // all x reads done before h1 writes clobber H
      write_h1<7>(acc, H, w * 16 + q * 4, l15);
    }
    __syncthreads();

    // ---- layer2: h1(K=256) -> h2, tanh (in place)
    {
      f32x4 acc[7];
      layer_mm1<HID, 7>(W2e, b2v, H, l15, q, acc);
      __syncthreads();  // all h1 reads done before h2 writes
      write_h1<7>(acc, H, w * 16 + q * 4, l15);
    }
    __syncthreads();

    // ---- layer3: h2(K=256) -> out; wave does tiles (m3, ntA) and (m3, nt1)
    {
      f32x4 acc[2];
      acc[0] = blv; acc[1] = blv;
      f32x4 wbuf[3][2];
      wbuf[0][0] = *(const f32x4*)(Wle);
      wbuf[0][1] = *(const f32x4*)(Wle + 4);
      wbuf[1][0] = *(const f32x4*)(Wle + 32);
      wbuf[1][1] = *(const f32x4*)(Wle + 36);
#pragma unroll
      for (int ks = 0; ks < 8; ks++) {
        if (ks + 2 < 8) {
          wbuf[(ks + 2) % 3][0] = *(const f32x4*)(Wle + (ks + 2) * 32);
          wbuf[(ks + 2) % 3][1] = *(const f32x4*)(Wle + (ks + 2) * 32 + 4);
        }
        short8 a = cvt8w(wbuf[ks % 3][0], wbuf[ks % 3][1]);
        short8 bA = *(const short8*)&H[(ntA * 16 + l15) * HP + ks * 32 + q * 8];
        short8 bB = *(const short8*)&H[(nt1 * 16 + l15) * HP + ks * 32 + q * 8];
        acc[0] = __builtin_amdgcn_mfma_f32_16x16x32_bf16(a, bA, acc[0], 0, 0, 0);
        acc[1] = __builtin_amdgcn_mfma_f32_16x16x32_bf16(a, bB, acc[1], 0, 0, 0);
      }
      {
        int gm = mt0 + ntA * 16 + l15;
        if (gm < cnt) {
          int r = rows[beg + gm];
          *(f32x4*)(out + (size_t)r * OUT_DIM + m3 * 16 + q * 4) = acc[0];
        }
      }
      if (ntA + 4 < 7) {
        int gm = mt0 + nt1 * 16 + l15;
        if (gm < cnt) {
          int r = rows[beg + gm];
          *(f32x4*)(out + (size_t)r * OUT_DIM + m3 * 16 + q * 4) = acc[1];
        }
      }
    }
  }
}

// ---------------- launcher ----------------

extern "C" void kernel_launch(void* const* d_in, const int* in_sizes, int n_in,
                              void* d_out, int out_size, void* d_ws, size_t ws_size,
                              hipStream_t stream) {
  const float* x   = (const float*)d_in[0];
  const int*   ind = (const int*)d_in[1];
  const float* W1  = (const float*)d_in[2];
  const float* b1  = (const float*)d_in[3];
  const float* W2  = (const float*)d_in[4];
  const float* b2  = (const float*)d_in[5];
  const float* Wl  = (const float*)d_in[6];
  const float* bl  = (const float*)d_in[7];
  float* out = (float*)d_out;

  int* offsets = (int*)d_ws;        // 257 ints
  int* rows    = (int*)d_ws + 260;  // 16384 ints

  prep_k<<<1, 1024, 0, stream>>>(ind, rows, offsets);
  mlp_k<<<NEXP, 1024, 0, stream>>>(x, W1, b1, W2, b2, Wl, bl, rows, offsets, out);
}